// Round 8
// baseline (2738.369 us; speedup 1.0000x reference)
//
#include <hip/hip_runtime.h>

// EdgeCNN (DynamicEdgeConv): N=20000, F=64, H=128, K=6 (incl self). All f32.
// ROUND-8: tile-min pruning. Rounds 3-7 showed the allocator mishandles top-k
// lists live across barriers (remat -> AGPR demotion -> 46B/lane/tile scratch
// spill, r7: WRITE 1.16GB). New invariant: NO list crosses a barrier.
//  A: MFMA pass keeps only a per-(row,64j-tile) MIN (1 reg, branchless) -> f16
//     into LDS M[64][313].
//  B: per row tau = 6th-smallest tile-min + 0.75 margin (>=7 sigma of bf16-dot
//     error; superset proof: 6 distinct closer tiles otherwise -> contradiction).
//  C: per row (1 wave) scan tiles with min<=tau (~6-10), exact f32 re-eval
//     (round-3-validated chain), per-lane ins6 (barrier-free region) + lex
//     butterfly -> final top-6. No rescue kernel, no buffers; ws need 3.2 MB.

#define N_NODES 20000
#define FDIM 64
#define KNN 6
#define HID 128
#define N_PAD 20480
#define R_PAD 20032          // 313 * 64
#define TILE_CNT 313
#define LDS_STRIDE 72        // ushorts per staged row (144 B)
#define MARGIN_SCAN 0.75f

typedef __bf16 v8bf __attribute__((ext_vector_type(8)));
typedef float f32x4 __attribute__((ext_vector_type(4)));
union FragU { uint4 u; v8bf v; };
union H16 { _Float16 h; unsigned short u; };

__device__ __forceinline__ unsigned short f2bf_rne(float f) {
  union { float f; unsigned int u; } c; c.f = f;
  return (unsigned short)((c.u + 0x7fffu + ((c.u >> 16) & 1u)) >> 16);
}

// Sorted-ascending 6-slot insert, strict '<' (ascending-j stream per lane =>
// lowest-j wins ties, matching jax.lax.top_k).
__device__ __forceinline__ void ins6(float d, int j, float (&bd)[6], int (&bj)[6]) {
  if (d < bd[5]) {
    const bool c0 = d < bd[0], c1 = d < bd[1], c2 = d < bd[2];
    const bool c3 = d < bd[3], c4 = d < bd[4];
    bd[5] = c4 ? bd[4] : d;              bj[5] = c4 ? bj[4] : j;
    bd[4] = c4 ? (c3 ? bd[3] : d) : bd[4]; bj[4] = c4 ? (c3 ? bj[3] : j) : bj[4];
    bd[3] = c3 ? (c2 ? bd[2] : d) : bd[3]; bj[3] = c3 ? (c2 ? bj[2] : j) : bj[3];
    bd[2] = c2 ? (c1 ? bd[1] : d) : bd[2]; bj[2] = c2 ? (c1 ? bj[1] : j) : bj[2];
    bd[1] = c1 ? (c0 ? bd[0] : d) : bd[1]; bj[1] = c1 ? (c0 ? bj[0] : j) : bj[1];
    bd[0] = c0 ? d : bd[0];              bj[0] = c0 ? j : bj[0];
  }
}

// Values-only sorted insert (phase B: 6 smallest tile-mins).
__device__ __forceinline__ void ins6v(float d, float (&bd)[6]) {
  if (d < bd[5]) {
    const bool c0 = d < bd[0], c1 = d < bd[1], c2 = d < bd[2];
    const bool c3 = d < bd[3], c4 = d < bd[4];
    bd[5] = c4 ? bd[4] : d;
    bd[4] = c4 ? (c3 ? bd[3] : d) : bd[4];
    bd[3] = c3 ? (c2 ? bd[2] : d) : bd[3];
    bd[2] = c2 ? (c1 ? bd[1] : d) : bd[2];
    bd[1] = c1 ? (c0 ? bd[0] : d) : bd[1];
    bd[0] = c0 ? d : bd[0];
  }
}

// Lexicographic (d, then j) insert for the cross-lane butterfly merge.
__device__ __forceinline__ void ins6_lex(float d, int j, float (&bd)[6], int (&bj)[6]) {
  bool c[6];
#pragma unroll
  for (int k = 0; k < 6; ++k)
    c[k] = (d < bd[k]) || (d == bd[k] && j < bj[k]);
#pragma unroll
  for (int k = 5; k >= 1; --k) {
    bd[k] = c[k] ? (c[k - 1] ? bd[k - 1] : d) : bd[k];
    bj[k] = c[k] ? (c[k - 1] ? bj[k - 1] : j) : bj[k];
  }
  bd[0] = c[0] ? d : bd[0];
  bj[0] = c[0] ? j : bj[0];
}

__global__ void sq_kernel(const float* __restrict__ x, float* __restrict__ sq) {
  const int i = blockIdx.x * blockDim.x + threadIdx.x;
  if (i >= N_NODES) return;
  const float4* r4 = (const float4*)(x + (size_t)i * FDIM);
  float s = 0.f;
#pragma unroll
  for (int q = 0; q < 16; ++q) {
    const float4 a = r4[q];
    s = fmaf(a.x, a.x, s); s = fmaf(a.y, a.y, s);
    s = fmaf(a.z, a.z, s); s = fmaf(a.w, a.w, s);
  }
  sq[i] = s;
}

// x (f32) -> xhi (bf16 rne), rows >= N zero-padded to R_PAD.
__global__ void split_kernel(const float* __restrict__ x,
                             unsigned short* __restrict__ xhi) {
  const int t = blockIdx.x * blockDim.x + threadIdx.x;
  if (t >= R_PAD * (FDIM / 4)) return;
  const int row = t >> 4;
  const int q = t & 15;
  float4 v = make_float4(0.f, 0.f, 0.f, 0.f);
  if (row < N_NODES) v = *(const float4*)(x + (size_t)row * FDIM + q * 4);
  ushort4 h;
  h.x = f2bf_rne(v.x); h.y = f2bf_rne(v.y);
  h.z = f2bf_rne(v.z); h.w = f2bf_rne(v.w);
  *(ushort4*)(xhi + (size_t)row * FDIM + q * 4) = h;
}

__global__ __launch_bounds__(256) void knn_fused_kernel(
    const float* __restrict__ x, const unsigned short* __restrict__ xhi,
    const float* __restrict__ sq, int* __restrict__ knn_idx) {
  __shared__ __align__(16) unsigned short sh[64 * LDS_STRIDE];
  __shared__ __align__(16) float sqs[64];
  __shared__ unsigned short M_lds[64][TILE_CNT];  // f16 tile-mins
  __shared__ float tau_lds[64];
  __shared__ __align__(16) float lds_xi[4][FDIM];

  const int tid = threadIdx.x;
  const int lane = tid & 63;
  const int wave = tid >> 6;
  const int c = lane & 15;
  const int quad = lane >> 4;
  const int iblk = blockIdx.x * 64;
  const int i_mine = iblk + wave * 16 + c;  // phase-A center row of this lane

  // B-operand (resident): xi fragment. i_mine < R_PAD always; padded rows zero.
  v8bf xi0, xi1;
  {
    const size_t g = (size_t)i_mine * FDIM + quad * 8;
    FragU f;
    f.u = *(const uint4*)(xhi + g);      xi0 = f.v;
    f.u = *(const uint4*)(xhi + g + 32); xi1 = f.v;
  }

  // ---- Phase A: per-(row, tile) min of approx metric sq_j - 2*dot_bf16 ----
  for (int tile = 0; tile < TILE_CNT; ++tile) {
    const int jbase = tile * 64;
    __syncthreads();
    {
      const int jr = tid >> 2, sg = tid & 3;
      const int j = jbase + jr;             // < R_PAD always
      const int lb = jr * LDS_STRIDE + sg * 16;
      const size_t g = (size_t)j * FDIM + sg * 16;
      const uint4 h0 = *(const uint4*)(xhi + g);
      const uint4 h1 = *(const uint4*)(xhi + g + 8);
      *(uint4*)(sh + lb) = h0;
      *(uint4*)(sh + lb + 8) = h1;
      if (tid < 64) {
        const int j2 = jbase + tid;
        sqs[tid] = (j2 < N_NODES) ? sq[j2] : __builtin_inff();
      }
    }
    __syncthreads();

    float mn = __builtin_inff();
#pragma unroll
    for (int n0 = 0; n0 < 64; n0 += 16) {
      const int aro = (n0 + c) * LDS_STRIDE + quad * 8;
      FragU f;
      v8bf a0, a1;
      f.u = *(const uint4*)(sh + aro);      a0 = f.v;
      f.u = *(const uint4*)(sh + aro + 32); a1 = f.v;
      f32x4 acc = {0.f, 0.f, 0.f, 0.f};
      acc = __builtin_amdgcn_mfma_f32_16x16x32_bf16(a0, xi0, acc, 0, 0, 0);
      acc = __builtin_amdgcn_mfma_f32_16x16x32_bf16(a1, xi1, acc, 0, 0, 0);
      const float4 s4 = *(const float4*)&sqs[n0 + quad * 4];
      mn = fminf(mn, fmaf(-2.f, acc[0], s4.x));
      mn = fminf(mn, fmaf(-2.f, acc[1], s4.y));
      mn = fminf(mn, fmaf(-2.f, acc[2], s4.z));
      mn = fminf(mn, fmaf(-2.f, acc[3], s4.w));
    }
    // combine the 4 quads that share row c
    mn = fminf(mn, __shfl_xor(mn, 16, 64));
    mn = fminf(mn, __shfl_xor(mn, 32, 64));
    if (quad == 0) {
      H16 hh; hh.h = (_Float16)mn;
      M_lds[wave * 16 + c][tile] = hh.u;
    }
  }
  __syncthreads();

  // ---- Phase B: per-row tau = 6th-smallest tile-min + margin ----
  if (wave == 0) {
    float b6[6];
#pragma unroll
    for (int k = 0; k < 6; ++k) b6[k] = __builtin_inff();
    for (int t = 0; t < TILE_CNT; ++t) {
      H16 hh; hh.u = M_lds[lane][t];
      ins6v((float)hh.h, b6);
    }
    tau_lds[lane] = b6[5] + MARGIN_SCAN;
  }
  __syncthreads();

  // ---- Phase C: per row (one wave), exact f32 eval of selected tiles ----
  for (int rr = 0; rr < 16; ++rr) {
    const int row = wave * 16 + rr;
    const int i = iblk + row;
    if (i >= N_NODES) continue;  // wave-uniform
    if (lane < 16) {
      const float4 v = ((const float4*)(x + (size_t)i * FDIM))[lane];
      *(float4*)&lds_xi[wave][lane * 4] = v;
    }
    const float tauv = tau_lds[row];
    const float sqi = sq[i];
    float bd[6]; int bj[6];
#pragma unroll
    for (int k = 0; k < 6; ++k) { bd[k] = __builtin_inff(); bj[k] = 0; }

    for (int tb = 0; tb < TILE_CNT; tb += 64) {
      const int t = tb + lane;
      bool sel = false;
      if (t < TILE_CNT) {
        H16 hh; hh.u = M_lds[row][t];
        sel = ((float)hh.h) <= tauv;
      }
      unsigned long long mask = __ballot(sel);
      while (mask) {
        const int t2 = __ffsll(mask) - 1;
        mask &= (mask - 1);
        const int j = (tb + t2) * 64 + lane;
        float d = __builtin_inff();
        if (j < N_NODES) {
          const float4* xj4 = (const float4*)(x + (size_t)j * FDIM);
          const float4* xi4 = (const float4*)&lds_xi[wave][0];
          float dot = 0.f;
#pragma unroll
          for (int q = 0; q < 16; ++q) {
            const float4 a = xi4[q];
            const float4 b = xj4[q];
            dot = fmaf(a.x, b.x, dot); dot = fmaf(a.y, b.y, dot);
            dot = fmaf(a.z, b.z, dot); dot = fmaf(a.w, b.w, dot);
          }
          d = fmaf(-2.f, dot, sqi + sq[j]);  // round-3-validated exact chain
        }
        ins6(d, j, bd, bj);  // per-lane j strictly ascending
      }
    }
    // 64-lane lexicographic butterfly merge -> row top-6
#pragma unroll
    for (int m = 1; m <= 32; m <<= 1) {
      float od[6]; int oj[6];
#pragma unroll
      for (int k = 0; k < 6; ++k) {
        od[k] = __shfl_xor(bd[k], m, 64);
        oj[k] = __shfl_xor(bj[k], m, 64);
      }
#pragma unroll
      for (int k = 0; k < 6; ++k) ins6_lex(od[k], oj[k], bd, bj);
    }
    if (lane == 0) {
#pragma unroll
      for (int k = 0; k < KNN; ++k) knn_idx[(size_t)i * KNN + k] = bj[k];
    }
  }
}

__global__ __launch_bounds__(HID) void mlp_kernel(
    const float* __restrict__ x, const int* __restrict__ knn_idx,
    const float* __restrict__ W1, const float* __restrict__ b1,
    const float* __restrict__ W2, const float* __restrict__ b2,
    float* __restrict__ out) {
  __shared__ float xi_s[FDIM];
  __shared__ float xd_s[KNN][FDIM];
  __shared__ float h1_s[KNN][HID];
  __shared__ int nb[KNN];
  const int i = blockIdx.x;
  const int t = threadIdx.x;
  if (t < KNN) nb[t] = knn_idx[(size_t)i * KNN + t];
  if (t < FDIM) xi_s[t] = x[(size_t)i * FDIM + t];
  __syncthreads();
  for (int e = t; e < KNN * FDIM; e += HID) {
    const int k = e >> 6;
    const int f = e & 63;
    xd_s[k][f] = x[(size_t)nb[k] * FDIM + f] - xi_s[f];
  }
  __syncthreads();
  float s0 = b1[t];
  for (int f = 0; f < FDIM; ++f) s0 = fmaf(xi_s[f], W1[f * HID + t], s0);
  float acc[KNN];
#pragma unroll
  for (int k = 0; k < KNN; ++k) acc[k] = s0;
  for (int f = 0; f < FDIM; ++f) {
    const float w = W1[(FDIM + f) * HID + t];
#pragma unroll
    for (int k = 0; k < KNN; ++k) acc[k] = fmaf(xd_s[k][f], w, acc[k]);
  }
#pragma unroll
  for (int k = 0; k < KNN; ++k) h1_s[k][t] = fmaxf(acc[k], 0.f);
  __syncthreads();
  float acc2[KNN];
  const float bb = b2[t];
#pragma unroll
  for (int k = 0; k < KNN; ++k) acc2[k] = bb;
  for (int h = 0; h < HID; ++h) {
    const float w = W2[h * HID + t];
#pragma unroll
    for (int k = 0; k < KNN; ++k) acc2[k] = fmaf(h1_s[k][h], w, acc2[k]);
  }
  float m = acc2[0];
#pragma unroll
  for (int k = 1; k < KNN; ++k) m = fmaxf(m, acc2[k]);
  out[(size_t)i * HID + t] = m;
}

extern "C" void kernel_launch(void* const* d_in, const int* in_sizes, int n_in,
                              void* d_out, int out_size, void* d_ws, size_t ws_size,
                              hipStream_t stream) {
  const float* x  = (const float*)d_in[0];
  // d_in[1] = edge_index (int64): unused by the reference
  const float* W1 = (const float*)d_in[2];
  const float* b1 = (const float*)d_in[3];
  const float* W2 = (const float*)d_in[4];
  const float* b2 = (const float*)d_in[5];
  float* out = (float*)d_out;

  // ws: [sq N_PAD f32 @0][knn N*K i32 @81920][xhi R_PAD*64 bf16 @655360]
  // total 3,219,456 B — always fits (ws >= 10.4 MB proven in round 3).
  char* ws = (char*)d_ws;
  float* sq = (float*)ws;
  int* knn = (int*)(ws + 81920);
  unsigned short* xhi = (unsigned short*)(ws + 655360);

  sq_kernel<<<dim3((N_NODES + 255) / 256), dim3(256), 0, stream>>>(x, sq);
  split_kernel<<<dim3((R_PAD * 16 + 255) / 256), dim3(256), 0, stream>>>(x, xhi);
  knn_fused_kernel<<<dim3(TILE_CNT), dim3(256), 0, stream>>>(x, xhi, sq, knn);
  mlp_kernel<<<dim3(N_NODES), dim3(HID), 0, stream>>>(x, knn, W1, b1, W2, b2,
                                                      out);
}

// Round 9
// 1245.380 us; speedup vs baseline: 2.1988x; 2.1988x over previous
//
#include <hip/hip_runtime.h>

// EdgeCNN (DynamicEdgeConv): N=20000, F=64, H=128, K=6 (incl self). All f32.
// ROUND-9: barrier-free MFMA filter. r7/r8 showed the allocator spills ~12
// dwords of per-lane state around EVERY __syncthreads in a streaming loop
// (r7 WRITE 1.16GB, r8 1.19GB = 47B/lane/tile at 838GB/s = the whole runtime).
// Fix: no barriers, no LDS. xhi (2.5MB bf16) is L2-resident; each wave loads
// B-side (xj rows) directly from global. Transposed MFMA: lane owns ONE center
// (12-reg list). nc=2 chunks x 4 quad-classes -> 48 exact-superset candidates
// per row, re-ranked by the proven exact-f32 rescue (lex (d,j) = jax top_k).

#define N_NODES 20000
#define FDIM 64
#define KNN 6
#define HID 128
#define N_PAD 20480
#define R_PAD 20032          // 313 * 64
#define NCH 2                // j-chunks (R_PAD/NCH must be multiple of 16)

typedef __bf16 v8bf __attribute__((ext_vector_type(8)));
typedef float f32x4 __attribute__((ext_vector_type(4)));
union FragU { uint4 u; v8bf v; };

__device__ __forceinline__ unsigned short f2bf_rne(float f) {
  union { float f; unsigned int u; } c; c.f = f;
  return (unsigned short)((c.u + 0x7fffu + ((c.u >> 16) & 1u)) >> 16);
}

// Sorted-ascending 6-slot insert, strict '<' (ascending-j stream per lane =>
// lowest-j wins ties, matching jax.lax.top_k).
__device__ __forceinline__ void ins6(float d, int j, float (&bd)[6], int (&bj)[6]) {
  if (d < bd[5]) {
    const bool c0 = d < bd[0], c1 = d < bd[1], c2 = d < bd[2];
    const bool c3 = d < bd[3], c4 = d < bd[4];
    bd[5] = c4 ? bd[4] : d;              bj[5] = c4 ? bj[4] : j;
    bd[4] = c4 ? (c3 ? bd[3] : d) : bd[4]; bj[4] = c4 ? (c3 ? bj[3] : j) : bj[4];
    bd[3] = c3 ? (c2 ? bd[2] : d) : bd[3]; bj[3] = c3 ? (c2 ? bj[2] : j) : bj[3];
    bd[2] = c2 ? (c1 ? bd[1] : d) : bd[2]; bj[2] = c2 ? (c1 ? bj[1] : j) : bj[2];
    bd[1] = c1 ? (c0 ? bd[0] : d) : bd[1]; bj[1] = c1 ? (c0 ? bj[0] : j) : bj[1];
    bd[0] = c0 ? d : bd[0];              bj[0] = c0 ? j : bj[0];
  }
}

// Lexicographic (d, then j) insert for unordered candidate streams (rescue).
__device__ __forceinline__ void ins6_lex(float d, int j, float (&bd)[6], int (&bj)[6]) {
  bool c[6];
#pragma unroll
  for (int k = 0; k < 6; ++k)
    c[k] = (d < bd[k]) || (d == bd[k] && j < bj[k]);
#pragma unroll
  for (int k = 5; k >= 1; --k) {
    bd[k] = c[k] ? (c[k - 1] ? bd[k - 1] : d) : bd[k];
    bj[k] = c[k] ? (c[k - 1] ? bj[k - 1] : j) : bj[k];
  }
  bd[0] = c[0] ? d : bd[0];
  bj[0] = c[0] ? j : bj[0];
}

__global__ void sq_kernel(const float* __restrict__ x, float* __restrict__ sq) {
  const int i = blockIdx.x * blockDim.x + threadIdx.x;
  if (i >= N_NODES) return;
  const float4* r4 = (const float4*)(x + (size_t)i * FDIM);
  float s = 0.f;
#pragma unroll
  for (int q = 0; q < 16; ++q) {
    const float4 a = r4[q];
    s = fmaf(a.x, a.x, s); s = fmaf(a.y, a.y, s);
    s = fmaf(a.z, a.z, s); s = fmaf(a.w, a.w, s);
  }
  sq[i] = s;
}

// x (f32) -> xhi (bf16 rne), rows >= N zero-padded to R_PAD.
__global__ void split_kernel(const float* __restrict__ x,
                             unsigned short* __restrict__ xhi) {
  const int t = blockIdx.x * blockDim.x + threadIdx.x;
  if (t >= R_PAD * (FDIM / 4)) return;
  const int row = t >> 4;
  const int q = t & 15;
  float4 v = make_float4(0.f, 0.f, 0.f, 0.f);
  if (row < N_NODES) v = *(const float4*)(x + (size_t)row * FDIM + q * 4);
  ushort4 h;
  h.x = f2bf_rne(v.x); h.y = f2bf_rne(v.y);
  h.z = f2bf_rne(v.z); h.w = f2bf_rne(v.w);
  *(ushort4*)(xhi + (size_t)row * FDIM + q * 4) = h;
}

// Barrier-free MFMA filter. Wave handles 16 centers (ibase..ibase+15); lane
// (c,quad) owns center ibase+c and sees j = j0+quad*4+{0..3} per step.
// A = xj rows (global/L2), B = xi frag (resident). C: col=lane&15, row=quad*4+r.
__global__ __launch_bounds__(256) void knn_filter_kernel(
    const unsigned short* __restrict__ xhi, const float* __restrict__ sq,
    int* __restrict__ cand_j, int jchunk) {
  const int tid = threadIdx.x;
  const int lane = tid & 63;
  const int wave = tid >> 6;
  const int c = lane & 15;
  const int quad = lane >> 4;
  const int jc = blockIdx.y;
  const int i = blockIdx.x * 64 + wave * 16 + c;  // this lane's center

  // Resident B-operand: B[k=quad*8+jj][n=c] = xhi[i][quad*8+jj], two K=32 steps.
  v8bf xi0, xi1;
  {
    FragU f;
    const size_t g = (size_t)i * FDIM + quad * 8;
    f.u = *(const uint4*)(xhi + g);      xi0 = f.v;
    f.u = *(const uint4*)(xhi + g + 32); xi1 = f.v;
  }

  float bd[6]; int bj[6];
#pragma unroll
  for (int k = 0; k < 6; ++k) { bd[k] = __builtin_inff(); bj[k] = 0; }

  const int j0beg = jc * jchunk;
  const int j0end = j0beg + jchunk;

  // Software pipeline: loads for step t+1 issue before compute of step t.
  const unsigned short* ap = xhi + (size_t)(j0beg + c) * FDIM + quad * 8;
  const float* sp = sq + j0beg + quad * 4;
  uint4 na0 = *(const uint4*)ap;
  uint4 na1 = *(const uint4*)(ap + 32);
  float4 nsq = *(const float4*)sp;

  for (int j0 = j0beg; j0 < j0end; j0 += 16) {
    const uint4 ca0 = na0, ca1 = na1;
    const float4 csq = nsq;
    ap += 16 * FDIM;
    sp += 16;
    if (j0 + 16 < j0end) {  // wave-uniform branch
      na0 = *(const uint4*)ap;
      na1 = *(const uint4*)(ap + 32);
      nsq = *(const float4*)sp;
    }
    FragU f;
    f.u = ca0; const v8bf a0 = f.v;
    f.u = ca1; const v8bf a1 = f.v;
    f32x4 acc = {0.f, 0.f, 0.f, 0.f};
    acc = __builtin_amdgcn_mfma_f32_16x16x32_bf16(a0, xi0, acc, 0, 0, 0);
    acc = __builtin_amdgcn_mfma_f32_16x16x32_bf16(a1, xi1, acc, 0, 0, 0);
    const float s4[4] = {csq.x, csq.y, csq.z, csq.w};
#pragma unroll
    for (int r = 0; r < 4; ++r) {
      const int j = j0 + quad * 4 + r;
      // filter metric: sq_j - 2*dot_bf16 (sq_i constant per lane; rescue exact)
      float d = fmaf(-2.f, acc[r], s4[r]);
      d = (j < N_NODES) ? d : __builtin_inff();
      ins6(d, j, bd, bj);  // per-lane j strictly ascending
    }
  }

  if (i < N_NODES) {
    const int set = jc * 4 + quad;  // 8 disjoint j-classes per row
#pragma unroll
    for (int k = 0; k < KNN; ++k)
      cand_j[((size_t)set * KNN + k) * N_PAD + i] = bj[k];
  }
}

// Exact f32 re-rank of nsets*6 distinct candidates -> final top-6 per row.
// Sequential-FMA chain matches sq_kernel => self-distance exactly 0.
__global__ void knn_rescue_kernel(const float* __restrict__ x,
                                  const float* __restrict__ sq,
                                  const int* __restrict__ cand_j,
                                  int* __restrict__ knn_idx, int nsets) {
  const int i = blockIdx.x * blockDim.x + threadIdx.x;
  if (i >= N_NODES) return;
  const float4* xi4 = (const float4*)(x + (size_t)i * FDIM);
  const float sqi = sq[i];
  float bd[6]; int bj[6];
#pragma unroll
  for (int k = 0; k < 6; ++k) { bd[k] = __builtin_inff(); bj[k] = 0; }
  for (int s = 0; s < nsets; ++s) {
#pragma unroll
    for (int k = 0; k < KNN; ++k) {
      const int j = cand_j[((size_t)s * KNN + k) * N_PAD + i];
      const float4* xj4 = (const float4*)(x + (size_t)j * FDIM);
      float dot = 0.f;
#pragma unroll
      for (int q = 0; q < 16; ++q) {
        const float4 a = xi4[q];
        const float4 b = xj4[q];
        dot = fmaf(a.x, b.x, dot); dot = fmaf(a.y, b.y, dot);
        dot = fmaf(a.z, b.z, dot); dot = fmaf(a.w, b.w, dot);
      }
      const float d = fmaf(-2.f, dot, sqi + sq[j]);
      ins6_lex(d, j, bd, bj);  // candidates distinct by construction
    }
  }
#pragma unroll
  for (int k = 0; k < KNN; ++k) knn_idx[(size_t)i * KNN + k] = bj[k];
}

__global__ __launch_bounds__(HID) void mlp_kernel(
    const float* __restrict__ x, const int* __restrict__ knn_idx,
    const float* __restrict__ W1, const float* __restrict__ b1,
    const float* __restrict__ W2, const float* __restrict__ b2,
    float* __restrict__ out) {
  __shared__ float xi_s[FDIM];
  __shared__ float xd_s[KNN][FDIM];
  __shared__ float h1_s[KNN][HID];
  __shared__ int nb[KNN];
  const int i = blockIdx.x;
  const int t = threadIdx.x;
  if (t < KNN) nb[t] = knn_idx[(size_t)i * KNN + t];
  if (t < FDIM) xi_s[t] = x[(size_t)i * FDIM + t];
  __syncthreads();
  for (int e = t; e < KNN * FDIM; e += HID) {
    const int k = e >> 6;
    const int f = e & 63;
    xd_s[k][f] = x[(size_t)nb[k] * FDIM + f] - xi_s[f];
  }
  __syncthreads();
  float s0 = b1[t];
  for (int f = 0; f < FDIM; ++f) s0 = fmaf(xi_s[f], W1[f * HID + t], s0);
  float acc[KNN];
#pragma unroll
  for (int k = 0; k < KNN; ++k) acc[k] = s0;
  for (int f = 0; f < FDIM; ++f) {
    const float w = W1[(FDIM + f) * HID + t];
#pragma unroll
    for (int k = 0; k < KNN; ++k) acc[k] = fmaf(xd_s[k][f], w, acc[k]);
  }
#pragma unroll
  for (int k = 0; k < KNN; ++k) h1_s[k][t] = fmaxf(acc[k], 0.f);
  __syncthreads();
  float acc2[KNN];
  const float bb = b2[t];
#pragma unroll
  for (int k = 0; k < KNN; ++k) acc2[k] = bb;
  for (int h = 0; h < HID; ++h) {
    const float w = W2[h * HID + t];
#pragma unroll
    for (int k = 0; k < KNN; ++k) acc2[k] = fmaf(h1_s[k][h], w, acc2[k]);
  }
  float m = acc2[0];
#pragma unroll
  for (int k = 1; k < KNN; ++k) m = fmaxf(m, acc2[k]);
  out[(size_t)i * HID + t] = m;
}

extern "C" void kernel_launch(void* const* d_in, const int* in_sizes, int n_in,
                              void* d_out, int out_size, void* d_ws, size_t ws_size,
                              hipStream_t stream) {
  const float* x  = (const float*)d_in[0];
  // d_in[1] = edge_index (int64): unused by the reference
  const float* W1 = (const float*)d_in[2];
  const float* b1 = (const float*)d_in[3];
  const float* W2 = (const float*)d_in[4];
  const float* b2 = (const float*)d_in[5];
  float* out = (float*)d_out;

  // ws: [sq N_PAD f32 @0][knn @81920][xhi bf16 @655360][cand_j @3219456]
  // cand_j: nc*4 sets * 6 * N_PAD ints; nc=2 -> 3.93MB, total 7.15MB.
  // (ws >= 10.4MB: proven in round 3 where nc=10 chunk layout fit.)
  char* ws = (char*)d_ws;
  float* sq = (float*)ws;
  int* knn = (int*)(ws + 81920);
  unsigned short* xhi = (unsigned short*)(ws + 655360);
  int* cand_j = (int*)(ws + 3219456);

  int nc = NCH;
  if (ws_size < 3219456 + (size_t)NCH * 4 * KNN * N_PAD * 4) nc = 1;
  const int jchunk = R_PAD / nc;  // nc=2 -> 10016 (mult of 16); nc=1 -> 20032

  sq_kernel<<<dim3((N_NODES + 255) / 256), dim3(256), 0, stream>>>(x, sq);
  split_kernel<<<dim3((R_PAD * 16 + 255) / 256), dim3(256), 0, stream>>>(x, xhi);
  knn_filter_kernel<<<dim3(R_PAD / 64, nc), dim3(256), 0, stream>>>(
      xhi, sq, cand_j, jchunk);
  knn_rescue_kernel<<<dim3((N_NODES + 255) / 256), dim3(256), 0, stream>>>(
      x, sq, cand_j, knn, nc * 4);
  mlp_kernel<<<dim3(N_NODES), dim3(HID), 0, stream>>>(x, knn, W1, b1, W2, b2,
                                                      out);
}